// Round 4
// baseline (367.653 us; speedup 1.0000x reference)
//
#include <hip/hip_runtime.h>
#include <hip/hip_bf16.h>

// ConvCaps spectral routing.
//   activations[b,o] = sigmoid(lambda_max(G)/tr(G) - bias[o])
//   poses[b,o,:]     = top eigenvector of G, matching LAPACK ssyevd sign conventions.
// R3 hybrid: ssteqr scalar recurrence (d/e) in registers (R2-proven via passing
// activations); A / Zr / tau in LDS exactly as the R1-passing kernel (vector path
// reverted — R2's register-array vector path produced sign flips).

#define NSPAT 196

__device__ __forceinline__ float wsum64(float x) {
  x += __shfl_xor(x, 32);
  x += __shfl_xor(x, 16);
  x += __shfl_xor(x, 8);
  x += __shfl_xor(x, 4);
  x += __shfl_xor(x, 2);
  x += __shfl_xor(x, 1);
  return x;
}

// unrolled register-array select / predicated write (static indices -> stays in VGPRs)
__device__ __forceinline__ float rsel16(const float* A_, int idx) {
  float r = A_[0];
#pragma unroll
  for (int k = 1; k < 16; ++k)
    if (idx == k) r = A_[k];
  return r;
}
__device__ __forceinline__ void wsel16(float* A_, int idx, float v) {
#pragma unroll
  for (int k = 0; k < 16; ++k)
    if (idx == k) A_[k] = v;
}

// ---------------- kernel A: per-(b,l) moment matrices -----------------------
__global__ __launch_bounds__(256) void moments_kernel(const float* __restrict__ in,
                                                      float* __restrict__ Mout) {
  int b = blockIdx.x >> 5;
  int l = blockIdx.x & 31;
  __shared__ float ps[NSPAT][16];
  __shared__ float as2[NSPAT];
  int t = threadIdx.x;
  for (int j = t; j < NSPAT * 16; j += 256) {
    int s = j >> 4, p = j & 15;
    ps[s][p] = in[((size_t)(b * NSPAT + s)) * 544 + l * 16 + p];
  }
  for (int s = t; s < NSPAT; s += 256) {
    float a = in[((size_t)(b * NSPAT + s)) * 544 + 512 + l];
    as2[s] = a * a;
  }
  __syncthreads();
  int p = t >> 4, q = t & 15;
  float acc = 0.f;
  for (int s = 0; s < NSPAT; ++s) {
    acc += as2[s] * (ps[s][p] * ps[s][q]);
  }
  Mout[(size_t)blockIdx.x * 256 + t] = acc;
}

// ---------------- kernel B: contract moments with weights -> gram ----------
__global__ __launch_bounds__(256) void gram_kernel(const float* __restrict__ Min,
                                                   const float* __restrict__ W,
                                                   float* __restrict__ Gout) {
  int b = blockIdx.x >> 5;
  int o = blockIdx.x & 31;
  int t = threadIdx.x;
  __shared__ float Ms[256];
  __shared__ float Ws[16];
  int p = t >> 4, q = t & 15;
  int i1 = p >> 2, k1 = p & 3, i2 = q >> 2, k2 = q & 3;
  float acc = 0.f;
  for (int l = 0; l < 32; ++l) {
    Ms[t] = Min[((size_t)(b * 32 + l)) * 256 + t];
    if (t < 16) Ws[t] = W[((size_t)(l * 32 + o)) * 16 + t];
    __syncthreads();
    float sub = 0.f;
    for (int j2 = 0; j2 < 4; ++j2) {
      float inner = 0.f;
      for (int j = 0; j < 4; ++j)
        inner += Ws[j * 4 + k1] * Ms[(i1 * 4 + j) * 16 + (i2 * 4 + j2)];
      sub += Ws[j2 * 4 + k2] * inner;
    }
    acc += sub;
    __syncthreads();
  }
  Gout[(size_t)blockIdx.x * 256 + t] = acc;
}

// ---------------- LAPACK fp32 helpers (sign-faithful) ----------------------
#define EPSF    5.9604645e-08f   /* slamch('E') = 2^-24 */
#define EPS2F   (EPSF * EPSF)
#define SAFMINF 1.1754944e-38f   /* slamch('S') */

__device__ __forceinline__ float ssign(float a, float b) {
  return (b >= 0.f) ? fabsf(a) : -fabsf(a);
}

__device__ __forceinline__ float slapy2(float x, float y) {
  float xa = fabsf(x), ya = fabsf(y);
  float w = fmaxf(xa, ya), z = fminf(xa, ya);
  if (z == 0.f) return w;
  float t = z / w;
  return w * sqrtf(1.f + t * t);
}

// LAPACK >= 3.10 slartg convention (c >= 0, r carries sign of f)
__device__ __forceinline__ void slartg(float f, float g, float* c, float* s, float* r) {
  if (g == 0.f) {
    *c = 1.f; *s = 0.f; *r = f;
  } else if (f == 0.f) {
    *c = 0.f; *s = (g >= 0.f) ? 1.f : -1.f; *r = fabsf(g);
  } else {
    float d = sqrtf(f * f + g * g);
    *c = fabsf(f) / d;
    float rr = (f >= 0.f) ? d : -d;
    *s = g / rr;
    *r = rr;
  }
}

__device__ __forceinline__ void slaev2(float a, float b, float c,
                                       float* rt1, float* rt2, float* cs1, float* sn1) {
  float sm = a + c;
  float df = a - c;
  float adf = fabsf(df);
  float tb = b + b;
  float ab = fabsf(tb);
  float acmx, acmn;
  if (fabsf(a) > fabsf(c)) { acmx = a; acmn = c; } else { acmx = c; acmn = a; }
  float rt;
  if (adf > ab)      { float t = ab / adf; rt = adf * sqrtf(1.f + t * t); }
  else if (adf < ab) { float t = adf / ab; rt = ab * sqrtf(1.f + t * t); }
  else               { rt = ab * sqrtf(2.f); }
  int sgn1;
  if (sm < 0.f) {
    *rt1 = 0.5f * (sm - rt); sgn1 = -1;
    *rt2 = (acmx / *rt1) * acmn - (b / *rt1) * b;
  } else if (sm > 0.f) {
    *rt1 = 0.5f * (sm + rt); sgn1 = 1;
    *rt2 = (acmx / *rt1) * acmn - (b / *rt1) * b;
  } else {
    *rt1 = 0.5f * rt; *rt2 = -0.5f * rt; sgn1 = 1;
  }
  float cs; int sgn2;
  if (df >= 0.f) { cs = df + rt; sgn2 = 1; }
  else           { cs = df - rt; sgn2 = -1; }
  float acs = fabsf(cs);
  float c1, s1;
  if (acs > ab) {
    float ct = -tb / cs;
    s1 = 1.f / sqrtf(1.f + ct * ct);
    c1 = ct * s1;
  } else {
    if (ab == 0.f) { c1 = 1.f; s1 = 0.f; }
    else {
      float tn = -cs / tb;
      c1 = 1.f / sqrtf(1.f + tn * tn);
      s1 = tn * c1;
    }
  }
  if (sgn1 == sgn2) { float tn = c1; c1 = -s1; s1 = tn; }
  *cs1 = c1; *sn1 = s1;
}

// ---------------- kernel C: one wave per 16x16 eig problem -----------------
// ssytd2(lower) in LDS (R1-proven) -> ssteqr with d/e in registers (R2-proven
// eigenvalue path) + Zr rotation accumulation in LDS (R1-proven vector path)
// -> sormtr back-transform from LDS A/ttl (R1-proven).
__global__ __launch_bounds__(64) void eig_kernel(const float* __restrict__ G,
                                                 const float* __restrict__ bias,
                                                 float* __restrict__ out) {
  const int pid = blockIdx.x;   // b*32 + o
  const int lane = threadIdx.x;
  __shared__ float A[16][17];      // symmetric working matrix / householder vectors
  __shared__ float Zr[16][17];     // Z row-major: Zr[row][col]
  __shared__ float ttl[64][17];    // per-lane replicated tau

  // load + symmetrize (use lower triangle), init Z = I
  for (int k = 0; k < 4; ++k) {
    int t = lane + 64 * k;
    int r = t >> 4, c = t & 15;
    int rr = r >= c ? r : c;
    int cc = r >= c ? c : r;
    A[r][c] = G[(size_t)pid * 256 + rr * 16 + cc];
    Zr[r][c] = (r == c) ? 1.f : 0.f;
  }
  float trc = (lane < 16) ? G[(size_t)pid * 256 + lane * 17] : 0.f;
  float trace = wsum64(trc);
  __syncthreads();

  float d[16], e[16];
  e[15] = 0.f;

  // ---- ssytd2 (lower) ---- (R1 verbatim, except e[] goes to registers)
#pragma unroll
  for (int i = 0; i < 15; ++i) {
    float acol = (lane < 16) ? A[lane][i] : 0.f;
    float alpha = __shfl(acol, i + 1);
    float x = (lane >= i + 2 && lane < 16) ? acol : 0.f;
    float xns = wsum64(x * x);
    if (xns == 0.f) {
      e[i] = alpha;
      ttl[lane][i] = 0.f;
    } else {
      float beta = (alpha >= 0.f ? -1.f : 1.f) * sqrtf(alpha * alpha + xns);
      float taui = (beta - alpha) / beta;
      float scal = 1.f / (alpha - beta);
      float vreg = 0.f;
      if (lane == i + 1) vreg = 1.f;
      else if (lane >= i + 2 && lane < 16) {
        vreg = acol * scal;
        A[lane][i] = vreg;   // persist householder vector (lane-local write)
      }
      e[i] = beta;
      ttl[lane][i] = taui;
      // w = taui * A_sub * v
      float wr = 0.f;
#pragma unroll
      for (int cI = i + 1; cI < 16; ++cI) {
        float vc = __shfl(vreg, cI);
        if (lane >= i + 1 && lane < 16) wr += A[lane][cI] * vc;
      }
      wr *= taui;
      float dot = wsum64((lane >= i + 1 && lane < 16) ? wr * vreg : 0.f);
      float alpha2 = -0.5f * taui * dot;
      wr += alpha2 * vreg;
      // A_sub -= v w^T + w v^T
#pragma unroll
      for (int cI = i + 1; cI < 16; ++cI) {
        float wc = __shfl(wr, cI);
        float vc = __shfl(vreg, cI);
        if (lane >= i + 1 && lane < 16) A[lane][cI] -= vreg * wc + wr * vc;
      }
    }
  }

  // broadcast diagonal into uniform register d[]
  {
    float di = (lane < 16) ? A[lane][lane] : 0.f;
#pragma unroll
    for (int j = 0; j < 16; ++j) d[j] = __shfl(di, j);
  }

  // ---- ssteqr('I'): d/e scalar recurrence in registers, Zr in LDS ----
  {
    int l1 = 0, jtot = 0;
    const int nmaxit = 16 * 30;
    while (l1 <= 15) {
      if (l1 > 0) wsel16(e, l1 - 1, 0.f);
      // outer deflation scan
      int m0 = 15;
      {
        bool found = false;
#pragma unroll
        for (int k = 0; k < 15; ++k) {
          if (!found && k >= l1) {
            float tst = fabsf(e[k]);
            if (tst == 0.f) { m0 = k; found = true; }
            else if (tst <= (sqrtf(fabsf(d[k])) * sqrtf(fabsf(d[k + 1]))) * EPSF) {
              e[k] = 0.f; m0 = k; found = true;
            }
          }
        }
      }
      int l = l1, lsv = l1, lend = m0, lendsv = m0;
      l1 = m0 + 1;
      if (lend == l) continue;
      // anorm
      float an = 0.f;
#pragma unroll
      for (int k = 0; k < 16; ++k)
        if (k >= l && k <= lend) an = fmaxf(an, fabsf(d[k]));
#pragma unroll
      for (int k = 0; k < 15; ++k)
        if (k >= l && k < lend) an = fmaxf(an, fabsf(e[k]));
      if (an == 0.f) continue;
      if (fabsf(rsel16(d, lend)) < fabsf(rsel16(d, l))) { lend = lsv; l = lendsv; }

      if (lend > l) {
        // ----- QL -----
        for (;;) {
          int m;
          {
            bool f2 = false; int mt = 0;
#pragma unroll
            for (int k = 0; k < 15; ++k) {
              if (!f2 && k >= l && k < lend) {
                float tst = e[k] * e[k];
                if (tst <= (EPS2F * fabsf(d[k])) * fabsf(d[k + 1]) + SAFMINF) { mt = k; f2 = true; }
              }
            }
            m = f2 ? mt : lend;
          }
          if (m < lend) wsel16(e, m, 0.f);
          float p = rsel16(d, l);
          if (m == l) {
            l = l + 1;
            if (l <= lend) continue;
            break;
          }
          if (m == l + 1) {
            float rt1, rt2, c2, s2;
            slaev2(rsel16(d, l), rsel16(e, l), rsel16(d, l + 1), &rt1, &rt2, &c2, &s2);
            if (lane < 16) {
              float zj = Zr[lane][l], zj1 = Zr[lane][l + 1];
              Zr[lane][l]     = c2 * zj + s2 * zj1;
              Zr[lane][l + 1] = -s2 * zj + c2 * zj1;
            }
            wsel16(d, l, rt1); wsel16(d, l + 1, rt2); wsel16(e, l, 0.f);
            l += 2;
            if (l <= lend) continue;
            break;
          }
          if (jtot == nmaxit) break;
          jtot++;
          float g = (rsel16(d, l + 1) - p) / (2.f * rsel16(e, l));
          float r = slapy2(g, 1.f);
          g = rsel16(d, m) - p + rsel16(e, l) / (g + ssign(r, g));
          float s = 1.f, c = 1.f;
          p = 0.f;
#pragma unroll
          for (int i = 14; i >= 0; --i) {
            if (i <= m - 1 && i >= l) {
              float f = s * e[i];
              float bb = c * e[i];
              slartg(g, f, &c, &s, &r);
              if (i != m - 1) e[i + 1] = r;
              g = d[i + 1] - p;
              r = (d[i] - g) * s + 2.f * c * bb;
              p = s * r;
              d[i + 1] = g + p;
              g = c * r - bb;
              if (lane < 16) {  // stored rotation (c, -s), slasr 'R','V','B'
                float zj = Zr[lane][i], zj1 = Zr[lane][i + 1];
                Zr[lane][i]     = c * zj - s * zj1;
                Zr[lane][i + 1] = s * zj + c * zj1;
              }
            }
          }
          wsel16(d, l, rsel16(d, l) - p);
          wsel16(e, l, g);
        }
      } else {
        // ----- QR -----
        for (;;) {
          int m;
          {
            bool f2 = false; int mt = 0;
#pragma unroll
            for (int k = 15; k >= 1; --k) {
              if (!f2 && k <= l && k > lend) {
                float tst = e[k - 1] * e[k - 1];
                if (tst <= (EPS2F * fabsf(d[k])) * fabsf(d[k - 1]) + SAFMINF) { mt = k; f2 = true; }
              }
            }
            m = f2 ? mt : lend;
          }
          if (m > lend) wsel16(e, m - 1, 0.f);
          float p = rsel16(d, l);
          if (m == l) {
            l = l - 1;
            if (l >= lend) continue;
            break;
          }
          if (m == l - 1) {
            float rt1, rt2, c2, s2;
            slaev2(rsel16(d, l - 1), rsel16(e, l - 1), rsel16(d, l), &rt1, &rt2, &c2, &s2);
            if (lane < 16) {
              float zj = Zr[lane][l - 1], zj1 = Zr[lane][l];
              Zr[lane][l - 1] = c2 * zj + s2 * zj1;
              Zr[lane][l]     = -s2 * zj + c2 * zj1;
            }
            wsel16(d, l - 1, rt1); wsel16(d, l, rt2); wsel16(e, l - 1, 0.f);
            l -= 2;
            if (l >= lend) continue;
            break;
          }
          if (jtot == nmaxit) break;
          jtot++;
          float g = (rsel16(d, l - 1) - p) / (2.f * rsel16(e, l - 1));
          float r = slapy2(g, 1.f);
          g = rsel16(d, m) - p + rsel16(e, l - 1) / (g + ssign(r, g));
          float s = 1.f, c = 1.f;
          p = 0.f;
#pragma unroll
          for (int i = 0; i <= 14; ++i) {
            if (i >= m && i <= l - 1) {
              float f = s * e[i];
              float bb = c * e[i];
              slartg(g, f, &c, &s, &r);
              if (i != m && i >= 1) e[i - 1] = r;
              g = d[i] - p;
              r = (d[i + 1] - g) * s + 2.f * c * bb;
              p = s * r;
              d[i] = g + p;
              g = c * r - bb;
              if (lane < 16) {  // stored rotation (c, s), slasr 'R','V','F'
                float zj = Zr[lane][i], zj1 = Zr[lane][i + 1];
                Zr[lane][i]     = c * zj + s * zj1;
                Zr[lane][i + 1] = -s * zj + c * zj1;
              }
            }
          }
          wsel16(d, l, rsel16(d, l) - p);
          wsel16(e, l - 1, g);
        }
      }
    }
  }

  // top eigenvalue/vector
  int kmax = 0;
  float dmax = d[0];
#pragma unroll
  for (int j = 1; j < 16; ++j) {
    if (d[j] > dmax) { dmax = d[j]; kmax = j; }
  }
  float vreg = (lane < 16) ? Zr[lane][kmax] : 0.f;
  // back-transform: v := H(0) H(1) ... H(14) v  (apply H(14) first) — R1 verbatim
  for (int i = 14; i >= 0; --i) {
    float taui = ttl[lane][i];
    if (taui == 0.f) continue;
    float contrib;
    if (lane == i + 1) contrib = vreg;
    else if (lane >= i + 2 && lane < 16) contrib = A[lane][i] * vreg;
    else contrib = 0.f;
    float dot = wsum64(contrib);
    float td = taui * dot;
    if (lane == i + 1) vreg -= td;
    else if (lane >= i + 2 && lane < 16) vreg -= td * A[lane][i];
  }

  float act = 1.f / (1.f + expf(-(dmax / trace - bias[pid & 31])));
  if (lane == 0) out[pid] = act;
  if (lane < 16) out[512 + pid * 16 + lane] = vreg;
}

extern "C" void kernel_launch(void* const* d_in, const int* in_sizes, int n_in,
                              void* d_out, int out_size, void* d_ws, size_t ws_size,
                              hipStream_t stream) {
  const float* in   = (const float*)d_in[0];   // [16,14,14,544] fp32
  const float* W    = (const float*)d_in[1];   // [1,32,32,4,4] fp32
  const float* bias = (const float*)d_in[2];   // [32] fp32
  float* out = (float*)d_out;

  float* Mbuf = (float*)d_ws;            // 512*256 floats = 512 KB
  float* Gbuf = Mbuf + 512 * 256;        // 512*256 floats = 512 KB

  moments_kernel<<<512, 256, 0, stream>>>(in, Mbuf);
  gram_kernel<<<512, 256, 0, stream>>>(Mbuf, W, Gbuf);
  eig_kernel<<<512, 64, 0, stream>>>(Gbuf, bias, out);
}

// Round 6
// 259.024 us; speedup vs baseline: 1.4194x; 1.4194x over previous
//
#include <hip/hip_runtime.h>
#include <hip/hip_bf16.h>

// ConvCaps spectral routing.
//   activations[b,o] = sigmoid(lambda_max(G)/tr(G) - bias[o])
//   poses[b,o,:]     = top eigenvector of G, matching LAPACK ssyevd sign conventions.
// R5: eig = R1-exact (proven-passing) with ONE change: per-rotation sweep reads
// (and m-find/shift reads) come from a loop-top snapshot via v_readlane instead of
// dependent LDS loads. LAPACK's sweeps only read pre-sweep d/e values (writes stay
// strictly past the read front), so readlane values are bit-identical to R1's LDS
// reads. All writes/scans/2x2/Zr/tau/back-transform are R1-verbatim.
// gram: stage all 32 l-slices once (1 barrier instead of 64).

#define NSPAT 196

__device__ __forceinline__ float wsum64(float x) {
  x += __shfl_xor(x, 32);
  x += __shfl_xor(x, 16);
  x += __shfl_xor(x, 8);
  x += __shfl_xor(x, 4);
  x += __shfl_xor(x, 2);
  x += __shfl_xor(x, 1);
  return x;
}

// wave-uniform lane read: v_readlane_b32 (SGPR result, ~4cyc, no LDS traffic)
__device__ __forceinline__ float rlanef(float x, int i) {
  return __int_as_float(__builtin_amdgcn_readlane(__float_as_int(x), i));
}

// ---------------- kernel A: per-(b,l) moment matrices -----------------------
__global__ __launch_bounds__(256) void moments_kernel(const float* __restrict__ in,
                                                      float* __restrict__ Mout) {
  int b = blockIdx.x >> 5;
  int l = blockIdx.x & 31;
  __shared__ float ps[NSPAT][16];
  __shared__ float as2[NSPAT];
  int t = threadIdx.x;
  for (int j = t; j < NSPAT * 16; j += 256) {
    int s = j >> 4, p = j & 15;
    ps[s][p] = in[((size_t)(b * NSPAT + s)) * 544 + l * 16 + p];
  }
  for (int s = t; s < NSPAT; s += 256) {
    float a = in[((size_t)(b * NSPAT + s)) * 544 + 512 + l];
    as2[s] = a * a;
  }
  __syncthreads();
  int p = t >> 4, q = t & 15;
  float acc = 0.f;
  for (int s = 0; s < NSPAT; ++s) {
    acc += as2[s] * (ps[s][p] * ps[s][q]);
  }
  Mout[(size_t)blockIdx.x * 256 + t] = acc;
}

// ---------------- kernel B: contract moments with weights -> gram ----------
// Single staging phase (32 KB Ms + 2 KB Ws), one barrier. FP accumulation order
// identical to the R1/R3-passing two-phase version (l ascending, then j2, j).
__global__ __launch_bounds__(256) void gram_kernel(const float* __restrict__ Min,
                                                   const float* __restrict__ W,
                                                   float* __restrict__ Gout) {
  int b = blockIdx.x >> 5;
  int o = blockIdx.x & 31;
  int t = threadIdx.x;
  __shared__ float Ms[32][256];
  __shared__ float Ws[32][16];
  for (int l = 0; l < 32; ++l)
    Ms[l][t] = Min[((size_t)(b * 32 + l)) * 256 + t];
  for (int j = t; j < 32 * 16; j += 256)
    Ws[j >> 4][j & 15] = W[((size_t)((j >> 4) * 32 + o)) * 16 + (j & 15)];
  __syncthreads();
  int p = t >> 4, q = t & 15;
  int i1 = p >> 2, k1 = p & 3, i2 = q >> 2, k2 = q & 3;
  float acc = 0.f;
  for (int l = 0; l < 32; ++l) {
    float sub = 0.f;
    for (int j2 = 0; j2 < 4; ++j2) {
      float inner = 0.f;
      for (int j = 0; j < 4; ++j)
        inner += Ws[l][j * 4 + k1] * Ms[l][(i1 * 4 + j) * 16 + (i2 * 4 + j2)];
      sub += Ws[l][j2 * 4 + k2] * inner;
    }
    acc += sub;
  }
  Gout[(size_t)blockIdx.x * 256 + t] = acc;
}

// ---------------- LAPACK fp32 helpers (sign-faithful) ----------------------
#define EPSF    5.9604645e-08f   /* slamch('E') = 2^-24 */
#define EPS2F   (EPSF * EPSF)
#define SAFMINF 1.1754944e-38f   /* slamch('S') */

__device__ __forceinline__ float ssign(float a, float b) {
  return (b >= 0.f) ? fabsf(a) : -fabsf(a);
}

__device__ __forceinline__ float slapy2(float x, float y) {
  float xa = fabsf(x), ya = fabsf(y);
  float w = fmaxf(xa, ya), z = fminf(xa, ya);
  if (z == 0.f) return w;
  float t = z / w;
  return w * sqrtf(1.f + t * t);
}

// LAPACK >= 3.10 slartg convention (c >= 0, r carries sign of f)
__device__ __forceinline__ void slartg(float f, float g, float* c, float* s, float* r) {
  if (g == 0.f) {
    *c = 1.f; *s = 0.f; *r = f;
  } else if (f == 0.f) {
    *c = 0.f; *s = (g >= 0.f) ? 1.f : -1.f; *r = fabsf(g);
  } else {
    float d = sqrtf(f * f + g * g);
    *c = fabsf(f) / d;
    float rr = (f >= 0.f) ? d : -d;
    *s = g / rr;
    *r = rr;
  }
}

__device__ __forceinline__ void slaev2(float a, float b, float c,
                                       float* rt1, float* rt2, float* cs1, float* sn1) {
  float sm = a + c;
  float df = a - c;
  float adf = fabsf(df);
  float tb = b + b;
  float ab = fabsf(tb);
  float acmx, acmn;
  if (fabsf(a) > fabsf(c)) { acmx = a; acmn = c; } else { acmx = c; acmn = a; }
  float rt;
  if (adf > ab)      { float t = ab / adf; rt = adf * sqrtf(1.f + t * t); }
  else if (adf < ab) { float t = adf / ab; rt = ab * sqrtf(1.f + t * t); }
  else               { rt = ab * sqrtf(2.f); }
  int sgn1;
  if (sm < 0.f) {
    *rt1 = 0.5f * (sm - rt); sgn1 = -1;
    *rt2 = (acmx / *rt1) * acmn - (b / *rt1) * b;
  } else if (sm > 0.f) {
    *rt1 = 0.5f * (sm + rt); sgn1 = 1;
    *rt2 = (acmx / *rt1) * acmn - (b / *rt1) * b;
  } else {
    *rt1 = 0.5f * rt; *rt2 = -0.5f * rt; sgn1 = 1;
  }
  float cs; int sgn2;
  if (df >= 0.f) { cs = df + rt; sgn2 = 1; }
  else           { cs = df - rt; sgn2 = -1; }
  float acs = fabsf(cs);
  float c1, s1;
  if (acs > ab) {
    float ct = -tb / cs;
    s1 = 1.f / sqrtf(1.f + ct * ct);
    c1 = ct * s1;
  } else {
    if (ab == 0.f) { c1 = 1.f; s1 = 0.f; }
    else {
      float tn = -cs / tb;
      c1 = 1.f / sqrtf(1.f + tn * tn);
      s1 = tn * c1;
    }
  }
  if (sgn1 == sgn2) { float tn = c1; c1 = -s1; s1 = tn; }
  *cs1 = c1; *sn1 = s1;
}

// ---------------- kernel C: one wave per 16x16 eig problem -----------------
// R1 structure: ssytd2(lower) + ssteqr('I') + sormtr, LDS state throughout.
// R5 delta: dsn/esn snapshots at QL/QR loop tops; sweep + m-find + shift READS
// via rlanef (values proven identical to R1's LDS reads). Writes stay in LDS.
__global__ __launch_bounds__(64) void eig_kernel(const float* __restrict__ G,
                                                 const float* __restrict__ bias,
                                                 float* __restrict__ out) {
  const int pid = blockIdx.x;   // b*32 + o
  const int lane = threadIdx.x;
  const int row = lane & 15;
  __shared__ float A[16][17];      // symmetric working matrix / householder vectors
  __shared__ float Zr[16][17];     // Z row-major: Zr[row][col]
  __shared__ float ddl[64][17];    // per-lane replicated d
  __shared__ float eel[64][17];    // per-lane replicated e
  __shared__ float ttl[64][17];    // per-lane replicated tau

  // load + symmetrize (use lower triangle), init Z = I
  for (int k = 0; k < 4; ++k) {
    int t = lane + 64 * k;
    int r = t >> 4, c = t & 15;
    int rr = r >= c ? r : c;
    int cc = r >= c ? c : r;
    A[r][c] = G[(size_t)pid * 256 + rr * 16 + cc];
    Zr[r][c] = (r == c) ? 1.f : 0.f;
  }
  float trc = (lane < 16) ? G[(size_t)pid * 256 + lane * 17] : 0.f;
  float trace = wsum64(trc);
  __syncthreads();

  // ---- ssytd2 (lower) ----
  for (int i = 0; i < 15; ++i) {
    float acol = (lane < 16) ? A[lane][i] : 0.f;
    float alpha = __shfl(acol, i + 1);
    float x = (lane >= i + 2 && lane < 16) ? acol : 0.f;
    float xns = wsum64(x * x);
    if (xns == 0.f) {
      eel[lane][i] = alpha;
      ttl[lane][i] = 0.f;
      continue;
    }
    float beta = (alpha >= 0.f ? -1.f : 1.f) * sqrtf(alpha * alpha + xns);
    float taui = (beta - alpha) / beta;
    float scal = 1.f / (alpha - beta);
    float vreg = 0.f;
    if (lane == i + 1) vreg = 1.f;
    else if (lane >= i + 2 && lane < 16) {
      vreg = acol * scal;
      A[lane][i] = vreg;   // persist householder vector (lane-local write)
    }
    eel[lane][i] = beta;
    ttl[lane][i] = taui;
    // w = taui * A_sub * v
    float wr = 0.f;
    for (int cI = i + 1; cI < 16; ++cI) {
      float vc = __shfl(vreg, cI);
      if (lane >= i + 1 && lane < 16) wr += A[lane][cI] * vc;
    }
    wr *= taui;
    float dot = wsum64((lane >= i + 1 && lane < 16) ? wr * vreg : 0.f);
    float alpha2 = -0.5f * taui * dot;
    wr += alpha2 * vreg;
    // A_sub -= v w^T + w v^T   (symmetric-exact full update, lane-local rows)
    for (int cI = i + 1; cI < 16; ++cI) {
      float wc = __shfl(wr, cI);
      float vc = __shfl(vreg, cI);
      if (lane >= i + 1 && lane < 16) A[lane][cI] -= vreg * wc + wr * vc;
    }
  }

  // gather d into per-lane replicated arrays
  float di = (lane < 16) ? A[lane][lane] : 0.f;
  for (int j = 0; j < 16; ++j) ddl[lane][j] = __shfl(di, j);

  float* dd = ddl[lane];
  float* ee = eel[lane];
  ee[15] = 0.f;   // pad slot (never read by logic; keeps snapshot poison-free)

  // ---- ssteqr('I') ----
  int m, l, lsv, lend, lendsv;
  int jtot = 0;
  const int nmaxit = 16 * 30;
  int l1 = 0;
  float dsn, esn;   // loop-top snapshots: lane j holds d[j] / e[j]

outer:
  if (l1 > 15) goto done;
  if (l1 > 0) ee[l1 - 1] = 0.f;
  {
    int mm;
    for (mm = l1; mm < 15; ++mm) {
      float tst = fabsf(ee[mm]);
      if (tst == 0.f) break;
      if (tst <= (sqrtf(fabsf(dd[mm])) * sqrtf(fabsf(dd[mm + 1]))) * EPSF) {
        ee[mm] = 0.f;
        break;
      }
    }
    m = mm;
  }
  l = l1; lsv = l; lend = m; lendsv = lend;
  l1 = m + 1;
  if (lend == l) goto outer;
  {
    float an = 0.f;
    for (int k2 = l; k2 <= lend; ++k2) an = fmaxf(an, fabsf(dd[k2]));
    for (int k2 = l; k2 < lend; ++k2) an = fmaxf(an, fabsf(ee[k2]));
    if (an == 0.f) goto outer;
  }
  if (fabsf(dd[lend]) < fabsf(dd[l])) { lend = lsv; l = lendsv; }

  if (lend > l) {
    // ----- QL -----
ql_top:
    dsn = dd[row];   // refresh snapshot (current == pre-sweep values)
    esn = ee[row];
    {
      int mm;
      for (mm = l; mm < lend; ++mm) {
        float eI = rlanef(esn, mm);
        float tst = eI * eI;
        if (tst <= (EPS2F * fabsf(rlanef(dsn, mm))) * fabsf(rlanef(dsn, mm + 1)) + SAFMINF) break;
      }
      m = mm;
    }
    if (m < lend) ee[m] = 0.f;
    {
      float p = dd[l];
      if (m == l) {
        dd[l] = p;
        l = l + 1;
        if (l <= lend) goto ql_top;
        goto blk_done;
      }
      if (m == l + 1) {
        float rt1, rt2, c2, s2;
        slaev2(dd[l], ee[l], dd[l + 1], &rt1, &rt2, &c2, &s2);
        if (lane < 16) {
          float zj = Zr[lane][l], zj1 = Zr[lane][l + 1];
          Zr[lane][l]     = c2 * zj + s2 * zj1;
          Zr[lane][l + 1] = -s2 * zj + c2 * zj1;
        }
        dd[l] = rt1; dd[l + 1] = rt2; ee[l] = 0.f;
        l += 2;
        if (l <= lend) goto ql_top;
        goto blk_done;
      }
      if (jtot == nmaxit) goto blk_done;
      jtot++;
      // shift (reads pre-sweep values; e[m]=0 write above doesn't alias: l<m, l+1<=m)
      float g = (rlanef(dsn, l + 1) - p) / (2.f * rlanef(esn, l));
      float r = slapy2(g, 1.f);
      g = rlanef(dsn, m) - p + rlanef(esn, l) / (g + ssign(r, g));
      float s = 1.f, c = 1.f;
      p = 0.f;
      for (int i = m - 1; i >= l; --i) {
        // pre-sweep reads (QL writes only d[i+2..m], e[i+2..m-1] so far)
        float eI = rlanef(esn, i);
        float f = s * eI;
        float bb = c * eI;
        slartg(g, f, &c, &s, &r);
        if (i != m - 1) ee[i + 1] = r;
        g = rlanef(dsn, i + 1) - p;
        r = (rlanef(dsn, i) - g) * s + 2.f * c * bb;
        p = s * r;
        dd[i + 1] = g + p;
        g = c * r - bb;
        if (lane < 16) {  // stored rotation (c, -s), slasr 'R','V','B'
          float zj = Zr[lane][i], zj1 = Zr[lane][i + 1];
          Zr[lane][i]     = c * zj - s * zj1;
          Zr[lane][i + 1] = s * zj + c * zj1;
        }
      }
      dd[l] -= p;
      ee[l] = g;
    }
    goto ql_top;
  } else {
    // ----- QR -----
qr_top:
    dsn = dd[row];
    esn = ee[row];
    {
      int mm;
      for (mm = l; mm > lend; --mm) {
        float eI = rlanef(esn, mm - 1);
        float tst = eI * eI;
        if (tst <= (EPS2F * fabsf(rlanef(dsn, mm))) * fabsf(rlanef(dsn, mm - 1)) + SAFMINF) break;
      }
      m = mm;
    }
    if (m > lend) ee[m - 1] = 0.f;
    {
      float p = dd[l];
      if (m == l) {
        dd[l] = p;
        l = l - 1;
        if (l >= lend) goto qr_top;
        goto blk_done;
      }
      if (m == l - 1) {
        float rt1, rt2, c2, s2;
        slaev2(dd[l - 1], ee[l - 1], dd[l], &rt1, &rt2, &c2, &s2);
        if (lane < 16) {
          float zj = Zr[lane][l - 1], zj1 = Zr[lane][l];
          Zr[lane][l - 1] = c2 * zj + s2 * zj1;
          Zr[lane][l]     = -s2 * zj + c2 * zj1;
        }
        dd[l - 1] = rt1; dd[l] = rt2; ee[l - 1] = 0.f;
        l -= 2;
        if (l >= lend) goto qr_top;
        goto blk_done;
      }
      if (jtot == nmaxit) goto blk_done;
      jtot++;
      // shift (e[m-1]=0 write doesn't alias e[l-1]: m < l-1)
      float g = (rlanef(dsn, l - 1) - p) / (2.f * rlanef(esn, l - 1));
      float r = slapy2(g, 1.f);
      g = rlanef(dsn, m) - p + rlanef(esn, l - 1) / (g + ssign(r, g));
      float s = 1.f, c = 1.f;
      p = 0.f;
      for (int i = m; i <= l - 1; ++i) {
        // pre-sweep reads (QR writes only d[m..i-1], e[m..i-2] so far)
        float eI = rlanef(esn, i);
        float f = s * eI;
        float bb = c * eI;
        slartg(g, f, &c, &s, &r);
        if (i != m) ee[i - 1] = r;
        g = rlanef(dsn, i) - p;
        r = (rlanef(dsn, i + 1) - g) * s + 2.f * c * bb;
        p = s * r;
        dd[i] = g + p;
        g = c * r - bb;
        if (lane < 16) {  // stored rotation (c, s), slasr 'R','V','F'
          float zj = Zr[lane][i], zj1 = Zr[lane][i + 1];
          Zr[lane][i]     = c * zj + s * zj1;
          Zr[lane][i + 1] = -s * zj + c * zj1;
        }
      }
      dd[l] -= p;
      ee[l - 1] = g;
    }
    goto qr_top;
  }
blk_done:
  goto outer;

done:;
  // top eigenvalue/vector (ascending sort's last column == argmax)
  int kmax = 0;
  float dmax = dd[0];
  for (int j = 1; j < 16; ++j) {
    float dj = dd[j];
    if (dj > dmax) { dmax = dj; kmax = j; }
  }
  float vreg = (lane < 16) ? Zr[lane][kmax] : 0.f;
  // back-transform: v := H(0) H(1) ... H(14) v  (apply H(14) first)
  for (int i = 14; i >= 0; --i) {
    float taui = ttl[lane][i];
    if (taui == 0.f) continue;
    float contrib;
    if (lane == i + 1) contrib = vreg;
    else if (lane >= i + 2 && lane < 16) contrib = A[lane][i] * vreg;
    else contrib = 0.f;
    float dot = wsum64(contrib);
    float td = taui * dot;
    if (lane == i + 1) vreg -= td;
    else if (lane >= i + 2 && lane < 16) vreg -= td * A[lane][i];
  }

  float act = 1.f / (1.f + expf(-(dmax / trace - bias[pid & 31])));
  if (lane == 0) out[pid] = act;
  if (lane < 16) out[512 + pid * 16 + lane] = vreg;
}

extern "C" void kernel_launch(void* const* d_in, const int* in_sizes, int n_in,
                              void* d_out, int out_size, void* d_ws, size_t ws_size,
                              hipStream_t stream) {
  const float* in   = (const float*)d_in[0];   // [16,14,14,544] fp32
  const float* W    = (const float*)d_in[1];   // [1,32,32,4,4] fp32
  const float* bias = (const float*)d_in[2];   // [32] fp32
  float* out = (float*)d_out;

  float* Mbuf = (float*)d_ws;            // 512*256 floats = 512 KB
  float* Gbuf = Mbuf + 512 * 256;        // 512*256 floats = 512 KB

  moments_kernel<<<512, 256, 0, stream>>>(in, Mbuf);
  gram_kernel<<<512, 256, 0, stream>>>(Mbuf, W, Gbuf);
  eig_kernel<<<512, 64, 0, stream>>>(Gbuf, bias, out);
}

// Round 7
// 256.957 us; speedup vs baseline: 1.4308x; 1.0080x over previous
//
#include <hip/hip_runtime.h>
#include <hip/hip_bf16.h>

// ConvCaps spectral routing.
//   activations[b,o] = sigmoid(lambda_max(G)/tr(G) - bias[o])
//   poses[b,o,:]     = top eigenvector of G, matching LAPACK ssyevd sign conventions.
// R6: ssteqr sweeps no longer touch Z. Rotations are LOGGED (c, sigma, i) and the
// needed eigenvector column is reconstructed afterwards by replaying the log in
// reverse onto e_kmax (lane-distributed, DPP-adjacent shfls). Decision path (d/e
// recurrence) is bit-identical to R5 (passing); only v's FP association changes
// (~n_rot*eps ~ 2e-5 absolute, far under the 1.9e-2 threshold).

#define NSPAT 196

__device__ __forceinline__ float wsum64(float x) {
  x += __shfl_xor(x, 32);
  x += __shfl_xor(x, 16);
  x += __shfl_xor(x, 8);
  x += __shfl_xor(x, 4);
  x += __shfl_xor(x, 2);
  x += __shfl_xor(x, 1);
  return x;
}

// wave-uniform lane read: v_readlane_b32 (SGPR result, no LDS traffic)
__device__ __forceinline__ float rlanef(float x, int i) {
  return __int_as_float(__builtin_amdgcn_readlane(__float_as_int(x), i));
}

// ---------------- kernel A: per-(b,l) moment matrices -----------------------
__global__ __launch_bounds__(256) void moments_kernel(const float* __restrict__ in,
                                                      float* __restrict__ Mout) {
  int b = blockIdx.x >> 5;
  int l = blockIdx.x & 31;
  __shared__ float ps[NSPAT][16];
  __shared__ float as2[NSPAT];
  int t = threadIdx.x;
  for (int j = t; j < NSPAT * 16; j += 256) {
    int s = j >> 4, p = j & 15;
    ps[s][p] = in[((size_t)(b * NSPAT + s)) * 544 + l * 16 + p];
  }
  for (int s = t; s < NSPAT; s += 256) {
    float a = in[((size_t)(b * NSPAT + s)) * 544 + 512 + l];
    as2[s] = a * a;
  }
  __syncthreads();
  int p = t >> 4, q = t & 15;
  float acc = 0.f;
  for (int s = 0; s < NSPAT; ++s) {
    acc += as2[s] * (ps[s][p] * ps[s][q]);
  }
  Mout[(size_t)blockIdx.x * 256 + t] = acc;
}

// ---------------- kernel B: contract moments with weights -> gram ----------
__global__ __launch_bounds__(256) void gram_kernel(const float* __restrict__ Min,
                                                   const float* __restrict__ W,
                                                   float* __restrict__ Gout) {
  int b = blockIdx.x >> 5;
  int o = blockIdx.x & 31;
  int t = threadIdx.x;
  __shared__ float Ms[32][256];
  __shared__ float Ws[32][16];
  for (int l = 0; l < 32; ++l)
    Ms[l][t] = Min[((size_t)(b * 32 + l)) * 256 + t];
  for (int j = t; j < 32 * 16; j += 256)
    Ws[j >> 4][j & 15] = W[((size_t)((j >> 4) * 32 + o)) * 16 + (j & 15)];
  __syncthreads();
  int p = t >> 4, q = t & 15;
  int i1 = p >> 2, k1 = p & 3, i2 = q >> 2, k2 = q & 3;
  float acc = 0.f;
  for (int l = 0; l < 32; ++l) {
    float sub = 0.f;
    for (int j2 = 0; j2 < 4; ++j2) {
      float inner = 0.f;
      for (int j = 0; j < 4; ++j)
        inner += Ws[l][j * 4 + k1] * Ms[l][(i1 * 4 + j) * 16 + (i2 * 4 + j2)];
      sub += Ws[l][j2 * 4 + k2] * inner;
    }
    acc += sub;
  }
  Gout[(size_t)blockIdx.x * 256 + t] = acc;
}

// ---------------- LAPACK fp32 helpers (sign-faithful) ----------------------
#define EPSF    5.9604645e-08f   /* slamch('E') = 2^-24 */
#define EPS2F   (EPSF * EPSF)
#define SAFMINF 1.1754944e-38f   /* slamch('S') */

__device__ __forceinline__ float ssign(float a, float b) {
  return (b >= 0.f) ? fabsf(a) : -fabsf(a);
}

__device__ __forceinline__ float slapy2(float x, float y) {
  float xa = fabsf(x), ya = fabsf(y);
  float w = fmaxf(xa, ya), z = fminf(xa, ya);
  if (z == 0.f) return w;
  float t = z / w;
  return w * sqrtf(1.f + t * t);
}

// LAPACK >= 3.10 slartg convention (c >= 0, r carries sign of f)
__device__ __forceinline__ void slartg(float f, float g, float* c, float* s, float* r) {
  if (g == 0.f) {
    *c = 1.f; *s = 0.f; *r = f;
  } else if (f == 0.f) {
    *c = 0.f; *s = (g >= 0.f) ? 1.f : -1.f; *r = fabsf(g);
  } else {
    float d = sqrtf(f * f + g * g);
    *c = fabsf(f) / d;
    float rr = (f >= 0.f) ? d : -d;
    *s = g / rr;
    *r = rr;
  }
}

__device__ __forceinline__ void slaev2(float a, float b, float c,
                                       float* rt1, float* rt2, float* cs1, float* sn1) {
  float sm = a + c;
  float df = a - c;
  float adf = fabsf(df);
  float tb = b + b;
  float ab = fabsf(tb);
  float acmx, acmn;
  if (fabsf(a) > fabsf(c)) { acmx = a; acmn = c; } else { acmx = c; acmn = a; }
  float rt;
  if (adf > ab)      { float t = ab / adf; rt = adf * sqrtf(1.f + t * t); }
  else if (adf < ab) { float t = adf / ab; rt = ab * sqrtf(1.f + t * t); }
  else               { rt = ab * sqrtf(2.f); }
  int sgn1;
  if (sm < 0.f) {
    *rt1 = 0.5f * (sm - rt); sgn1 = -1;
    *rt2 = (acmx / *rt1) * acmn - (b / *rt1) * b;
  } else if (sm > 0.f) {
    *rt1 = 0.5f * (sm + rt); sgn1 = 1;
    *rt2 = (acmx / *rt1) * acmn - (b / *rt1) * b;
  } else {
    *rt1 = 0.5f * rt; *rt2 = -0.5f * rt; sgn1 = 1;
  }
  float cs; int sgn2;
  if (df >= 0.f) { cs = df + rt; sgn2 = 1; }
  else           { cs = df - rt; sgn2 = -1; }
  float acs = fabsf(cs);
  float c1, s1;
  if (acs > ab) {
    float ct = -tb / cs;
    s1 = 1.f / sqrtf(1.f + ct * ct);
    c1 = ct * s1;
  } else {
    if (ab == 0.f) { c1 = 1.f; s1 = 0.f; }
    else {
      float tn = -cs / tb;
      c1 = 1.f / sqrtf(1.f + tn * tn);
      s1 = tn * c1;
    }
  }
  if (sgn1 == sgn2) { float tn = c1; c1 = -s1; s1 = tn; }
  *cs1 = c1; *sn1 = s1;
}

#define MAXLOG 1024

// ---------------- kernel C: one wave per 16x16 eig problem -----------------
// ssytd2(lower, LDS) -> ssteqr (d/e LDS-master + readlane snapshots; rotations
// LOGGED, no Z in sweeps) -> reverse replay builds Z[:,kmax] -> sormtr.
__global__ __launch_bounds__(64) void eig_kernel(const float* __restrict__ G,
                                                 const float* __restrict__ bias,
                                                 float* __restrict__ out) {
  const int pid = blockIdx.x;   // b*32 + o
  const int lane = threadIdx.x;
  const int row = lane & 15;
  __shared__ float A[16][17];      // working matrix / householder vectors
  __shared__ float ddl[64][17];    // per-lane replicated d
  __shared__ float eel[64][17];    // per-lane replicated e
  __shared__ float ttl[64][17];    // per-lane replicated tau
  __shared__ float2 logcs[MAXLOG]; // rotation log: (c, sigma)
  __shared__ int    logi[MAXLOG];  // rotation log: column index i

  // load + symmetrize (use lower triangle)
  for (int k = 0; k < 4; ++k) {
    int t = lane + 64 * k;
    int r = t >> 4, c = t & 15;
    int rr = r >= c ? r : c;
    int cc = r >= c ? c : r;
    A[r][c] = G[(size_t)pid * 256 + rr * 16 + cc];
  }
  float trc = (lane < 16) ? G[(size_t)pid * 256 + lane * 17] : 0.f;
  float trace = wsum64(trc);
  __syncthreads();

  // ---- ssytd2 (lower) ----
  for (int i = 0; i < 15; ++i) {
    float acol = (lane < 16) ? A[lane][i] : 0.f;
    float alpha = __shfl(acol, i + 1);
    float x = (lane >= i + 2 && lane < 16) ? acol : 0.f;
    float xns = wsum64(x * x);
    if (xns == 0.f) {
      eel[lane][i] = alpha;
      ttl[lane][i] = 0.f;
      continue;
    }
    float beta = (alpha >= 0.f ? -1.f : 1.f) * sqrtf(alpha * alpha + xns);
    float taui = (beta - alpha) / beta;
    float scal = 1.f / (alpha - beta);
    float vreg = 0.f;
    if (lane == i + 1) vreg = 1.f;
    else if (lane >= i + 2 && lane < 16) {
      vreg = acol * scal;
      A[lane][i] = vreg;   // persist householder vector (lane-local write)
    }
    eel[lane][i] = beta;
    ttl[lane][i] = taui;
    float wr = 0.f;
    for (int cI = i + 1; cI < 16; ++cI) {
      float vc = __shfl(vreg, cI);
      if (lane >= i + 1 && lane < 16) wr += A[lane][cI] * vc;
    }
    wr *= taui;
    float dot = wsum64((lane >= i + 1 && lane < 16) ? wr * vreg : 0.f);
    float alpha2 = -0.5f * taui * dot;
    wr += alpha2 * vreg;
    for (int cI = i + 1; cI < 16; ++cI) {
      float wc = __shfl(wr, cI);
      float vc = __shfl(vreg, cI);
      if (lane >= i + 1 && lane < 16) A[lane][cI] -= vreg * wc + wr * vc;
    }
  }

  // gather d into per-lane replicated arrays
  float di = (lane < 16) ? A[lane][lane] : 0.f;
  for (int j = 0; j < 16; ++j) ddl[lane][j] = __shfl(di, j);

  float* dd = ddl[lane];
  float* ee = eel[lane];
  ee[15] = 0.f;   // pad slot for snapshots

  // ---- ssteqr('I') ----
  int m, l, lsv, lend, lendsv;
  int jtot = 0;
  const int nmaxit = 16 * 30;
  int l1 = 0;
  int nrot = 0;
  float dsn, esn;   // snapshots: lane j holds d[j] / e[j]

outer:
  if (l1 > 15) goto done;
  if (l1 > 0) ee[l1 - 1] = 0.f;
  dsn = dd[row];   // outer-top snapshot (after the e zeroing above)
  esn = ee[row];
  {
    int mm;
    for (mm = l1; mm < 15; ++mm) {
      float eI = rlanef(esn, mm);
      float tst = fabsf(eI);
      if (tst == 0.f) break;
      if (tst <= (sqrtf(fabsf(rlanef(dsn, mm))) * sqrtf(fabsf(rlanef(dsn, mm + 1)))) * EPSF) {
        ee[mm] = 0.f;
        break;
      }
    }
    m = mm;
  }
  l = l1; lsv = l; lend = m; lendsv = lend;
  l1 = m + 1;
  if (lend == l) goto outer;
  {
    // anorm over [l, lend] (the scan's ee[m]=0 write is outside this range)
    float an = 0.f;
    for (int k2 = l; k2 <= lend; ++k2) an = fmaxf(an, fabsf(rlanef(dsn, k2)));
    for (int k2 = l; k2 < lend; ++k2) an = fmaxf(an, fabsf(rlanef(esn, k2)));
    if (an == 0.f) goto outer;
  }
  if (fabsf(rlanef(dsn, lend)) < fabsf(rlanef(dsn, l))) { lend = lsv; l = lendsv; }

  if (lend > l) {
    // ----- QL -----
ql_top:
    dsn = dd[row];   // refresh snapshot (pre-sweep values)
    esn = ee[row];
    {
      int mm;
      for (mm = l; mm < lend; ++mm) {
        float eI = rlanef(esn, mm);
        float tst = eI * eI;
        if (tst <= (EPS2F * fabsf(rlanef(dsn, mm))) * fabsf(rlanef(dsn, mm + 1)) + SAFMINF) break;
      }
      m = mm;
    }
    if (m < lend) ee[m] = 0.f;   // pre-snapshot reads below all use idx < m
    {
      float p = rlanef(dsn, l);
      if (m == l) {
        dd[l] = p;
        l = l + 1;
        if (l <= lend) goto ql_top;
        goto blk_done;
      }
      if (m == l + 1) {
        float rt1, rt2, c2, s2;
        slaev2(rlanef(dsn, l), rlanef(esn, l), rlanef(dsn, l + 1), &rt1, &rt2, &c2, &s2);
        if (lane == 0 && nrot < MAXLOG) { logcs[nrot] = make_float2(c2, -s2); logi[nrot] = l; }
        nrot++;
        dd[l] = rt1; dd[l + 1] = rt2; ee[l] = 0.f;
        l += 2;
        if (l <= lend) goto ql_top;
        goto blk_done;
      }
      if (jtot == nmaxit) goto blk_done;
      jtot++;
      float g = (rlanef(dsn, l + 1) - p) / (2.f * rlanef(esn, l));
      float r = slapy2(g, 1.f);
      g = rlanef(dsn, m) - p + rlanef(esn, l) / (g + ssign(r, g));
      float s = 1.f, c = 1.f;
      p = 0.f;
      for (int i = m - 1; i >= l; --i) {
        float eI = rlanef(esn, i);
        float f = s * eI;
        float bb = c * eI;
        slartg(g, f, &c, &s, &r);
        if (i != m - 1) ee[i + 1] = r;
        g = rlanef(dsn, i + 1) - p;
        r = (rlanef(dsn, i) - g) * s + 2.f * c * bb;
        p = s * r;
        dd[i + 1] = g + p;
        g = c * r - bb;
        if (lane == 0 && nrot < MAXLOG) { logcs[nrot] = make_float2(c, s); logi[nrot] = i; }  // QL: sigma=+s
        nrot++;
      }
      dd[l] = rlanef(dsn, l) - p;   // d[l] untouched by sweep writes
      ee[l] = g;
    }
    goto ql_top;
  } else {
    // ----- QR -----
qr_top:
    dsn = dd[row];
    esn = ee[row];
    {
      int mm;
      for (mm = l; mm > lend; --mm) {
        float eI = rlanef(esn, mm - 1);
        float tst = eI * eI;
        if (tst <= (EPS2F * fabsf(rlanef(dsn, mm))) * fabsf(rlanef(dsn, mm - 1)) + SAFMINF) break;
      }
      m = mm;
    }
    if (m > lend) ee[m - 1] = 0.f;   // reads below use idx >= m-? all >= m-1+1
    {
      float p = rlanef(dsn, l);
      if (m == l) {
        dd[l] = p;
        l = l - 1;
        if (l >= lend) goto qr_top;
        goto blk_done;
      }
      if (m == l - 1) {
        float rt1, rt2, c2, s2;
        slaev2(rlanef(dsn, l - 1), rlanef(esn, l - 1), rlanef(dsn, l), &rt1, &rt2, &c2, &s2);
        if (lane == 0 && nrot < MAXLOG) { logcs[nrot] = make_float2(c2, -s2); logi[nrot] = l - 1; }
        nrot++;
        dd[l - 1] = rt1; dd[l] = rt2; ee[l - 1] = 0.f;
        l -= 2;
        if (l >= lend) goto qr_top;
        goto blk_done;
      }
      if (jtot == nmaxit) goto blk_done;
      jtot++;
      float g = (rlanef(dsn, l - 1) - p) / (2.f * rlanef(esn, l - 1));
      float r = slapy2(g, 1.f);
      g = rlanef(dsn, m) - p + rlanef(esn, l - 1) / (g + ssign(r, g));
      float s = 1.f, c = 1.f;
      p = 0.f;
      for (int i = m; i <= l - 1; ++i) {
        float eI = rlanef(esn, i);
        float f = s * eI;
        float bb = c * eI;
        slartg(g, f, &c, &s, &r);
        if (i != m) ee[i - 1] = r;
        g = rlanef(dsn, i) - p;
        r = (rlanef(dsn, i + 1) - g) * s + 2.f * c * bb;
        p = s * r;
        dd[i] = g + p;
        g = c * r - bb;
        if (lane == 0 && nrot < MAXLOG) { logcs[nrot] = make_float2(c, -s); logi[nrot] = i; }  // QR: sigma=-s
        nrot++;
      }
      dd[l] = rlanef(dsn, l) - p;
      ee[l - 1] = g;
    }
    goto qr_top;
  }
blk_done:
  goto outer;

done:;
  // top eigenvalue index
  dsn = dd[row];
  int kmax = 0;
  float dmax = rlanef(dsn, 0);
  for (int j = 1; j < 16; ++j) {
    float dj = rlanef(dsn, j);
    if (dj > dmax) { dmax = dj; kmax = j; }
  }

  // reconstruct v = Z[:,kmax] by reverse replay: w = G_0(G_1(...(G_{n-1} e_kmax)))
  // applied as: for t = n-1..0: w = G_t * w, where
  //   (G*w)[i]   =  c*w[i] + sigma*w[i+1]
  //   (G*w)[i+1] = -sigma*w[i] + c*w[i+1]
  float w = (lane == kmax) ? 1.f : 0.f;
  {
    int t = nrot - 1;
    if (t > MAXLOG - 1) t = MAXLOG - 1;   // (overflow cannot happen for sane inputs)
    while (t >= 0) {
      int base = t & ~63;
      float2 cs = logcs[base + lane];   // lane k holds entry base+k
      int ii = logi[base + lane];
      for (int k = t - base; k >= 0; --k) {
        float c = rlanef(cs.x, k);
        float sg = rlanef(cs.y, k);
        int i = __builtin_amdgcn_readlane(ii, k);
        float wup = __shfl_up(w, 1);
        float wdn = __shfl_down(w, 1);
        float nw = w;
        if (lane == i) nw = c * w + sg * wdn;
        else if (lane == i + 1) nw = -sg * wup + c * w;
        w = nw;
      }
      t = base - 1;
    }
  }

  float vreg = (lane < 16) ? w : 0.f;
  // back-transform: v := H(0) H(1) ... H(14) v  (apply H(14) first)
  for (int i = 14; i >= 0; --i) {
    float taui = ttl[lane][i];
    if (taui == 0.f) continue;
    float contrib;
    if (lane == i + 1) contrib = vreg;
    else if (lane >= i + 2 && lane < 16) contrib = A[lane][i] * vreg;
    else contrib = 0.f;
    float dot = wsum64(contrib);
    float td = taui * dot;
    if (lane == i + 1) vreg -= td;
    else if (lane >= i + 2 && lane < 16) vreg -= td * A[lane][i];
  }

  float act = 1.f / (1.f + expf(-(dmax / trace - bias[pid & 31])));
  if (lane == 0) out[pid] = act;
  if (lane < 16) out[512 + pid * 16 + lane] = vreg;
}

extern "C" void kernel_launch(void* const* d_in, const int* in_sizes, int n_in,
                              void* d_out, int out_size, void* d_ws, size_t ws_size,
                              hipStream_t stream) {
  const float* in   = (const float*)d_in[0];   // [16,14,14,544] fp32
  const float* W    = (const float*)d_in[1];   // [1,32,32,4,4] fp32
  const float* bias = (const float*)d_in[2];   // [32] fp32
  float* out = (float*)d_out;

  float* Mbuf = (float*)d_ws;            // 512*256 floats = 512 KB
  float* Gbuf = Mbuf + 512 * 256;        // 512*256 floats = 512 KB

  moments_kernel<<<512, 256, 0, stream>>>(in, Mbuf);
  gram_kernel<<<512, 256, 0, stream>>>(Mbuf, W, Gbuf);
  eig_kernel<<<512, 64, 0, stream>>>(Gbuf, bias, out);
}